// Round 4
// baseline (63.987 us; speedup 1.0000x reference)
//
#include <hip/hip_runtime.h>
#include <hip/hip_bf16.h>

// Problem dims (fixed by reference): B=64 S=256 F=4 V=50257 H=768 D=512
#define M_TOT 16384   // B*S
#define K_TOT 768     // H
#define N_TOT 512     // D
#define BM 64
#define NT (K_TOT / 64)  // 12 K-steps

typedef __attribute__((ext_vector_type(8))) __bf16 bf16x8;
typedef __attribute__((ext_vector_type(4))) float f32x4;

static __device__ __forceinline__ ushort f2bf(float x) {
  union { float f; unsigned int u; } v; v.f = x;
  unsigned int r = v.u + 0x7fffu + ((v.u >> 16) & 1u);
  return (ushort)(r >> 16);
}
static __device__ __forceinline__ unsigned pack2(float lo, float hi) {
  return (unsigned)f2bf(lo) | ((unsigned)f2bf(hi) << 16);
}

// async global->LDS, 16B per lane; lds dest is wave-uniform base + lane*16
static __device__ __forceinline__ void load_lds16(const ushort* g, ushort* l) {
  __builtin_amdgcn_global_load_lds(
      (const __attribute__((address_space(1))) void*)g,
      (__attribute__((address_space(3))) void*)l, 16, 0, 0);
}

// ---------------------------------------------------------------------------
// Kernel 1: W[768][512] f32 -> Wt[512][768] bf16 (transpose + convert)
// ---------------------------------------------------------------------------
__global__ __launch_bounds__(256) void wt_kernel(const float* __restrict__ W,
                                                 ushort* __restrict__ Wt) {
  __shared__ float tile[64][65];
  const int t  = threadIdx.x;
  const int k0 = blockIdx.x * 64;
  const int n0 = blockIdx.y * 64;
#pragma unroll
  for (int i = 0; i < 4; ++i) {
    const int idx = t + i * 256;
    const int r = idx >> 4;
    const int c = (idx & 15) * 4;
    const float4 v =
        *reinterpret_cast<const float4*>(W + (size_t)(k0 + r) * N_TOT + n0 + c);
    tile[r][c + 0] = v.x; tile[r][c + 1] = v.y;
    tile[r][c + 2] = v.z; tile[r][c + 3] = v.w;
  }
  __syncthreads();
#pragma unroll
  for (int i = 0; i < 4; ++i) {
    const int idx = t + i * 256;
    const int rn = idx >> 4;
    const int ck = (idx & 15) * 4;
    ushort4 o;
    o.x = f2bf(tile[ck + 0][rn]);
    o.y = f2bf(tile[ck + 1][rn]);
    o.z = f2bf(tile[ck + 2][rn]);
    o.w = f2bf(tile[ck + 3][rn]);
    *reinterpret_cast<ushort4*>(Wt + (size_t)(n0 + rn) * K_TOT + k0 + ck) = o;
  }
}

// ---------------------------------------------------------------------------
// Kernel 2 (FUSED): gather+mean produces the A-tile in LDS on the fly;
// out[16384][512] = mean-gather(E, words) @ Wt^T + bias.
// 256 blocks (1/CU), 512 threads (8 waves, 2x4), BM=64 x BN=512, BK=64.
// B (Wt) double-buffered via global_load_lds; A double-buffered via
// reg-staged E gather (branchless mask-FMA) + linear ds_write_b128.
// ---------------------------------------------------------------------------
__global__ __launch_bounds__(512, 2) void fused_kernel(
    const int* __restrict__ words, const float* __restrict__ E,
    const ushort* __restrict__ Bt, const float* __restrict__ bias,
    float* __restrict__ out) {
  __shared__ ushort Bl[2][N_TOT * 64];  // 2 x 64 KB
  __shared__ ushort Al[2][BM * 64];     // 2 x 8 KB
  __shared__ int   eoff_l[BM][4];
  __shared__ float msk_l[BM][4];
  __shared__ float scl_l[BM];

  const int t    = threadIdx.x;
  const int lane = t & 63;
  const int w    = t >> 6;     // 0..7
  const int wr   = w >> 2;     // 0..1  (32 rows each)
  const int wc   = w & 3;      // 0..3  (128 cols each)
  const int bm   = blockIdx.x;

  // ---- per-row gather metadata (rows bm*64 .. +64) ----
  if (t < BM) {
    const int4 w4 =
        *reinterpret_cast<const int4*>(words + (size_t)(bm * BM + t) * 4);
    const int ids[4] = {w4.x, w4.y, w4.z, w4.w};
    float cnt = 0.f;
#pragma unroll
    for (int f = 0; f < 4; ++f) {
      eoff_l[t][f] = ids[f] * K_TOT;
      const float m = (ids[f] != 0) ? 1.f : 0.f;
      msk_l[t][f] = m;
      cnt += m;
    }
    scl_l[t] = (cnt > 0.f) ? (1.f / cnt) : 0.f;
  }
  __syncthreads();

  // ---- staging thread params (row sr, k-sub ss covers 8 consecutive k) ----
  const int sr = t >> 3;   // 0..63
  const int ss = t & 7;    // 0..7
  const float4* pf[4];
#pragma unroll
  for (int f = 0; f < 4; ++f)
    pf[f] = reinterpret_cast<const float4*>(E + eoff_l[sr][f] + ss * 8);
  const float m0 = msk_l[sr][0], m1 = msk_l[sr][1];
  const float m2 = msk_l[sr][2], m3 = msk_l[sr][3];
  const float scl = scl_l[sr];
  const ushort* bB = Bt + (size_t)sr * K_TOT + ss * 8;  // B staging base

  f32x4 acc[2][8];
#pragma unroll
  for (int m = 0; m < 2; ++m)
#pragma unroll
    for (int n = 0; n < 8; ++n) acc[m][n] = (f32x4){0.f, 0.f, 0.f, 0.f};

  float4 va[8];  // staged E slices: va[2f+h], h=0 -> k 0..3, h=1 -> k 4..7

#define A_LOAD(kt)                                                           \
  do {                                                                       \
    _Pragma("unroll") for (int f = 0; f < 4; ++f) {                          \
      va[2 * f + 0] = pf[f][(kt) * 16 + 0];                                  \
      va[2 * f + 1] = pf[f][(kt) * 16 + 1];                                  \
    }                                                                        \
  } while (0)

#define STAGE_B(dst, kt)                                                     \
  do {                                                                       \
    _Pragma("unroll") for (int i = 0; i < 8; ++i) {                          \
      load_lds16(bB + (size_t)i * 64 * K_TOT + (kt) * 64,                    \
                 &(dst)[(i * 512 + w * 64) * 8]);                            \
    }                                                                        \
  } while (0)

#define A_MATH(dst)                                                          \
  do {                                                                       \
    float s[8];                                                              \
    _Pragma("unroll") for (int j = 0; j < 4; ++j) {                          \
      s[j] = (va[0][j] * m0 + va[2][j] * m1 + va[4][j] * m2 + va[6][j] * m3) \
             * scl;                                                          \
      s[4 + j] =                                                             \
          (va[1][j] * m0 + va[3][j] * m1 + va[5][j] * m2 + va[7][j] * m3) *  \
          scl;                                                               \
    }                                                                        \
    uint4 o;                                                                 \
    o.x = pack2(s[0], s[1]); o.y = pack2(s[2], s[3]);                        \
    o.z = pack2(s[4], s[5]); o.w = pack2(s[6], s[7]);                        \
    *reinterpret_cast<uint4*>(&(dst)[sr * 64 + ss * 8]) = o;                 \
  } while (0)

#define COMPUTE(Ar, Br)                                                      \
  do {                                                                       \
    _Pragma("unroll") for (int kk = 0; kk < 2; ++kk) {                       \
      const int ks = kk * 4 + (lane >> 4);                                   \
      bf16x8 af[2], bfr[8];                                                  \
      _Pragma("unroll") for (int m = 0; m < 2; ++m)                          \
        af[m] = *reinterpret_cast<const bf16x8*>(                            \
            &(Ar)[(wr * 32 + m * 16 + (lane & 15)) * 64 + ks * 8]);          \
      _Pragma("unroll") for (int n = 0; n < 8; ++n)                          \
        bfr[n] = *reinterpret_cast<const bf16x8*>(                           \
            &(Br)[(wc * 128 + n * 16 + (lane & 15)) * 64 + ks * 8]);         \
      __builtin_amdgcn_s_setprio(1);                                         \
      _Pragma("unroll") for (int m = 0; m < 2; ++m)                          \
        _Pragma("unroll") for (int n = 0; n < 8; ++n)                        \
          acc[m][n] = __builtin_amdgcn_mfma_f32_16x16x32_bf16(               \
              af[m], bfr[n], acc[m][n], 0, 0, 0);                            \
      __builtin_amdgcn_s_setprio(0);                                         \
    }                                                                        \
  } while (0)

  // ---- prologue: stage tile 0 into buf 0 ----
  A_LOAD(0);
  STAGE_B(Bl[0], 0);
  A_MATH(Al[0]);
  __syncthreads();  // compiler drains vmcnt+lgkm before barrier

  int cur = 0;
  for (int kt = 0; kt < NT; ++kt) {
    const ushort* Ar = cur ? Al[1] : Al[0];
    const ushort* Br = cur ? Bl[1] : Bl[0];
    ushort* An = cur ? Al[0] : Al[1];
    ushort* Bn = cur ? Bl[0] : Bl[1];
    if (kt + 1 < NT) {
      A_LOAD(kt + 1);      // E loads first: A_MATH waits these, not the gloads
      STAGE_B(Bn, kt + 1); // async loads stay in flight until the barrier
    }
    COMPUTE(Ar, Br);
    if (kt + 1 < NT) A_MATH(An);
    __syncthreads();
    cur ^= 1;
  }
#undef A_LOAD
#undef STAGE_B
#undef A_MATH
#undef COMPUTE

  // ---- epilogue: C col = lane&15 (+16n), row = (lane>>4)*4 + j (+16m) ----
  const int col  = wc * 128 + (lane & 15);
  const int row0 = bm * BM + wr * 32 + ((lane >> 4) << 2);
#pragma unroll
  for (int n = 0; n < 8; ++n) {
    const float bv = bias[col + n * 16];
#pragma unroll
    for (int m = 0; m < 2; ++m) {
#pragma unroll
      for (int j = 0; j < 4; ++j) {
        __builtin_nontemporal_store(
            acc[m][n][j] + bv,
            &out[(size_t)(row0 + m * 16 + j) * N_TOT + col + n * 16]);
      }
    }
  }
}

// ---------------------------------------------------------------------------
extern "C" void kernel_launch(void* const* d_in, const int* in_sizes, int n_in,
                              void* d_out, int out_size, void* d_ws,
                              size_t ws_size, hipStream_t stream) {
  const int*   words = (const int*)d_in[0];
  const float* E     = (const float*)d_in[1];
  const float* W     = (const float*)d_in[2];
  const float* b     = (const float*)d_in[3];
  float* out = (float*)d_out;

  ushort* Wtws = (ushort*)d_ws;  // 512*768 bf16

  hipLaunchKernelGGL(wt_kernel, dim3(K_TOT / 64, N_TOT / 64), dim3(256), 0,
                     stream, W, Wtws);
  hipLaunchKernelGGL(fused_kernel, dim3(M_TOT / BM), dim3(512), 0, stream,
                     words, E, Wtws, b, out);
}

// Round 5
// 59.968 us; speedup vs baseline: 1.0670x; 1.0670x over previous
//
#include <hip/hip_runtime.h>
#include <hip/hip_bf16.h>

// Problem dims (fixed by reference): B=64 S=256 F=4 V=50257 H=768 D=512
#define M_TOT 16384   // B*S
#define K_TOT 768     // H
#define N_TOT 512     // D
#define BM 64
#define NT (K_TOT / 64)  // 12 K-steps

typedef __attribute__((ext_vector_type(8))) __bf16 bf16x8;
typedef __attribute__((ext_vector_type(4))) float f32x4;

static __device__ __forceinline__ ushort f2bf(float x) {
  union { float f; unsigned int u; } v; v.f = x;
  unsigned int r = v.u + 0x7fffu + ((v.u >> 16) & 1u);
  return (ushort)(r >> 16);
}
static __device__ __forceinline__ unsigned pack2(float lo, float hi) {
  return (unsigned)f2bf(lo) | ((unsigned)f2bf(hi) << 16);
}

// async global->LDS, 16B per lane; lds dest is wave-uniform base + lane*16
static __device__ __forceinline__ void load_lds16(const ushort* g, ushort* l) {
  __builtin_amdgcn_global_load_lds(
      (const __attribute__((address_space(1))) void*)g,
      (__attribute__((address_space(3))) void*)l, 16, 0, 0);
}

// ---------------------------------------------------------------------------
// Kernel 1: W[768][512] f32 -> Wt[512][768] bf16 (transpose + convert)
// ---------------------------------------------------------------------------
__global__ __launch_bounds__(256) void wt_kernel(const float* __restrict__ W,
                                                 ushort* __restrict__ Wt) {
  __shared__ float tile[64][65];
  const int t  = threadIdx.x;
  const int k0 = blockIdx.x * 64;
  const int n0 = blockIdx.y * 64;
#pragma unroll
  for (int i = 0; i < 4; ++i) {
    const int idx = t + i * 256;
    const int r = idx >> 4;
    const int c = (idx & 15) * 4;
    const float4 v =
        *reinterpret_cast<const float4*>(W + (size_t)(k0 + r) * N_TOT + n0 + c);
    tile[r][c + 0] = v.x; tile[r][c + 1] = v.y;
    tile[r][c + 2] = v.z; tile[r][c + 3] = v.w;
  }
  __syncthreads();
#pragma unroll
  for (int i = 0; i < 4; ++i) {
    const int idx = t + i * 256;
    const int rn = idx >> 4;
    const int ck = (idx & 15) * 4;
    ushort4 o;
    o.x = f2bf(tile[ck + 0][rn]);
    o.y = f2bf(tile[ck + 1][rn]);
    o.z = f2bf(tile[ck + 2][rn]);
    o.w = f2bf(tile[ck + 3][rn]);
    *reinterpret_cast<ushort4*>(Wt + (size_t)(n0 + rn) * K_TOT + k0 + ck) = o;
  }
}

// ---------------------------------------------------------------------------
// Kernel 2 (FUSED): out[16384][512] = mean-gather(E, words) @ Wt^T + bias.
// 256 blocks (1/CU), 512 threads (8 waves), BM=64 x BN=512, BK=64.
// Wave w computes the full 64 A-rows x cols [w*64, w*64+64)  (1x8 split).
// LDS tiles are XOR-swizzled at 16B-slot granularity: slot = seg ^ (row&7)
// (T2; kills the 16-way ds_read_b128 bank conflict of 128B-stride rows).
//  - A tile: reg-gathered from E, ds_write_b128 directly to swizzled slot.
//  - B tile: global_load_lds writes LDS linearly, so the per-lane GLOBAL
//    source is pre-swizzled (rule #21): lane covering LDS (row,seg) reads
//    global (row, seg^(row&7)); row&7 == (t>>3)&7 is per-thread constant.
// ---------------------------------------------------------------------------
__global__ __launch_bounds__(512, 2) void fused_kernel(
    const int* __restrict__ words, const float* __restrict__ E,
    const ushort* __restrict__ Bt, const float* __restrict__ bias,
    float* __restrict__ out) {
  __shared__ ushort Bl[2][N_TOT * 64];  // 2 x 64 KB
  __shared__ ushort Al[2][BM * 64];     // 2 x 8 KB
  __shared__ int   eoff_l[BM][4];
  __shared__ float msk_l[BM][4];
  __shared__ float scl_l[BM];

  const int t    = threadIdx.x;
  const int lane = t & 63;
  const int w    = t >> 6;     // 0..7: wave's 64-col slab
  const int bm   = blockIdx.x;

  // ---- per-row gather metadata (rows bm*64 .. +64) ----
  if (t < BM) {
    const int4 w4 =
        *reinterpret_cast<const int4*>(words + (size_t)(bm * BM + t) * 4);
    const int ids[4] = {w4.x, w4.y, w4.z, w4.w};
    float cnt = 0.f;
#pragma unroll
    for (int f = 0; f < 4; ++f) {
      eoff_l[t][f] = ids[f] * K_TOT;
      const float m = (ids[f] != 0) ? 1.f : 0.f;
      msk_l[t][f] = m;
      cnt += m;
    }
    scl_l[t] = (cnt > 0.f) ? (1.f / cnt) : 0.f;
  }
  __syncthreads();

  // ---- staging params: thread t covers (row sr, 16B-seg ss) of the tile ----
  const int sr = t >> 3;   // 0..63
  const int ss = t & 7;    // 0..7
  const int sw = ss ^ (sr & 7);  // swizzled slot
  const float4* pf[4];
#pragma unroll
  for (int f = 0; f < 4; ++f)
    pf[f] = reinterpret_cast<const float4*>(E + eoff_l[sr][f] + ss * 8);
  const float m0 = msk_l[sr][0], m1 = msk_l[sr][1];
  const float m2 = msk_l[sr][2], m3 = msk_l[sr][3];
  const float scl = scl_l[sr];
  // B staging: pre-swizzled global source (LDS dest stays linear)
  const ushort* bBsw = Bt + (size_t)sr * K_TOT + sw * 8;
  const int awoff = sr * 64 + sw * 8;  // swizzled A-tile write slot (elems)

  f32x4 acc[4][4];
#pragma unroll
  for (int m = 0; m < 4; ++m)
#pragma unroll
    for (int n = 0; n < 4; ++n) acc[m][n] = (f32x4){0.f, 0.f, 0.f, 0.f};

  float4 va[8];  // staged E slices: va[2f+h], h=0 -> k 0..3, h=1 -> k 4..7

#define A_LOAD(kt)                                                           \
  do {                                                                       \
    _Pragma("unroll") for (int f = 0; f < 4; ++f) {                          \
      va[2 * f + 0] = pf[f][(kt) * 16 + 0];                                  \
      va[2 * f + 1] = pf[f][(kt) * 16 + 1];                                  \
    }                                                                        \
  } while (0)

#define STAGE_B(dst, kt)                                                     \
  do {                                                                       \
    _Pragma("unroll") for (int i = 0; i < 8; ++i) {                          \
      load_lds16(bBsw + (size_t)i * 64 * K_TOT + (kt) * 64,                  \
                 &(dst)[(i * 512 + w * 64) * 8]);                            \
    }                                                                        \
  } while (0)

#define A_MATH(dst)                                                          \
  do {                                                                       \
    float s[8];                                                              \
    _Pragma("unroll") for (int j = 0; j < 4; ++j) {                          \
      s[j] = (va[0][j] * m0 + va[2][j] * m1 + va[4][j] * m2 + va[6][j] * m3) \
             * scl;                                                          \
      s[4 + j] =                                                             \
          (va[1][j] * m0 + va[3][j] * m1 + va[5][j] * m2 + va[7][j] * m3) *  \
          scl;                                                               \
    }                                                                        \
    uint4 o;                                                                 \
    o.x = pack2(s[0], s[1]); o.y = pack2(s[2], s[3]);                        \
    o.z = pack2(s[4], s[5]); o.w = pack2(s[6], s[7]);                        \
    *reinterpret_cast<uint4*>(&(dst)[awoff]) = o;                            \
  } while (0)

#define COMPUTE(Ar, Br)                                                      \
  do {                                                                       \
    _Pragma("unroll") for (int kk = 0; kk < 2; ++kk) {                       \
      const int ks = kk * 4 + (lane >> 4);                                   \
      const int sl = (ks ^ (lane & 7)) * 8;                                  \
      bf16x8 af[4], bfr[4];                                                  \
      _Pragma("unroll") for (int m = 0; m < 4; ++m)                          \
        af[m] = *reinterpret_cast<const bf16x8*>(                            \
            &(Ar)[(m * 16 + (lane & 15)) * 64 + sl]);                        \
      _Pragma("unroll") for (int n = 0; n < 4; ++n)                          \
        bfr[n] = *reinterpret_cast<const bf16x8*>(                           \
            &(Br)[(w * 64 + n * 16 + (lane & 15)) * 64 + sl]);               \
      __builtin_amdgcn_s_setprio(1);                                         \
      _Pragma("unroll") for (int m = 0; m < 4; ++m)                          \
        _Pragma("unroll") for (int n = 0; n < 4; ++n)                        \
          acc[m][n] = __builtin_amdgcn_mfma_f32_16x16x32_bf16(               \
              af[m], bfr[n], acc[m][n], 0, 0, 0);                            \
      __builtin_amdgcn_s_setprio(0);                                         \
    }                                                                        \
  } while (0)

  // ---- prologue: stage tile 0 into buf 0 ----
  A_LOAD(0);
  STAGE_B(Bl[0], 0);
  A_MATH(Al[0]);
  __syncthreads();  // compiler drains vmcnt+lgkm before barrier

  int cur = 0;
  for (int kt = 0; kt < NT; ++kt) {
    const ushort* Ar = cur ? Al[1] : Al[0];
    const ushort* Br = cur ? Bl[1] : Bl[0];
    ushort* An = cur ? Al[0] : Al[1];
    ushort* Bn = cur ? Bl[0] : Bl[1];
    if (kt + 1 < NT) {
      A_LOAD(kt + 1);      // E loads first: A_MATH waits these, not the gloads
      STAGE_B(Bn, kt + 1); // async loads stay in flight until the barrier
    }
    COMPUTE(Ar, Br);
    if (kt + 1 < NT) A_MATH(An);
    __syncthreads();
    cur ^= 1;
  }
#undef A_LOAD
#undef STAGE_B
#undef A_MATH
#undef COMPUTE

  // ---- epilogue: C col = lane&15 (+16n), row = (lane>>4)*4 + j (+16m) ----
  const int colBase = w * 64 + (lane & 15);
  const int row0    = bm * BM + ((lane >> 4) << 2);
#pragma unroll
  for (int n = 0; n < 4; ++n) {
    const float bv = bias[colBase + n * 16];
#pragma unroll
    for (int m = 0; m < 4; ++m) {
#pragma unroll
      for (int j = 0; j < 4; ++j) {
        __builtin_nontemporal_store(
            acc[m][n][j] + bv,
            &out[(size_t)(row0 + m * 16 + j) * N_TOT + colBase + n * 16]);
      }
    }
  }
}

// ---------------------------------------------------------------------------
extern "C" void kernel_launch(void* const* d_in, const int* in_sizes, int n_in,
                              void* d_out, int out_size, void* d_ws,
                              size_t ws_size, hipStream_t stream) {
  const int*   words = (const int*)d_in[0];
  const float* E     = (const float*)d_in[1];
  const float* W     = (const float*)d_in[2];
  const float* b     = (const float*)d_in[3];
  float* out = (float*)d_out;

  ushort* Wtws = (ushort*)d_ws;  // 512*768 bf16

  hipLaunchKernelGGL(wt_kernel, dim3(K_TOT / 64, N_TOT / 64), dim3(256), 0,
                     stream, W, Wtws);
  hipLaunchKernelGGL(fused_kernel, dim3(M_TOT / BM), dim3(512), 0, stream,
                     words, E, Wtws, b, out);
}

// Round 6
// 54.456 us; speedup vs baseline: 1.1750x; 1.1012x over previous
//
#include <hip/hip_runtime.h>
#include <hip/hip_bf16.h>

// Problem dims (fixed by reference): B=64 S=256 F=4 V=50257 H=768 D=512
#define M_TOT 16384   // B*S
#define K_TOT 768     // H
#define N_TOT 512     // D
#define BM 32         // rows per block
#define NT 12         // K_TOT / 64 K-chunks
#define NSLOT 96      // 16B-slots per A row (768*2B / 16B)

typedef __attribute__((ext_vector_type(8))) __bf16 bf16x8;
typedef __attribute__((ext_vector_type(4))) float f32x4;

static __device__ __forceinline__ ushort f2bf(float x) {
  union { float f; unsigned int u; } v; v.f = x;
  unsigned int r = v.u + 0x7fffu + ((v.u >> 16) & 1u);
  return (ushort)(r >> 16);
}
static __device__ __forceinline__ unsigned pack2(float lo, float hi) {
  return (unsigned)f2bf(lo) | ((unsigned)f2bf(hi) << 16);
}

// ---------------------------------------------------------------------------
// Kernel 1: W[768][512] f32 -> Wt_frag bf16 in fragment-major layout:
//   element W[k][col]  ->  Wt[ ((k>>3)*512 + col)*8 + (k&7) ]
// so an MFMA B-fragment (col, 8 consecutive k) is one contiguous 16B chunk,
// and 16 consecutive cols are 256B contiguous (coalesced per 16 lanes).
// ---------------------------------------------------------------------------
__global__ __launch_bounds__(256) void wt_kernel(const float* __restrict__ W,
                                                 ushort* __restrict__ Wt) {
  __shared__ float tile[64][65];
  const int t  = threadIdx.x;
  const int k0 = blockIdx.x * 64;
  const int n0 = blockIdx.y * 64;
#pragma unroll
  for (int i = 0; i < 4; ++i) {
    const int idx = t + i * 256;
    const int r = idx >> 4;
    const int c = (idx & 15) * 4;
    const float4 v =
        *reinterpret_cast<const float4*>(W + (size_t)(k0 + r) * N_TOT + n0 + c);
    tile[r][c + 0] = v.x; tile[r][c + 1] = v.y;
    tile[r][c + 2] = v.z; tile[r][c + 3] = v.w;
  }
  __syncthreads();
#pragma unroll
  for (int i = 0; i < 4; ++i) {
    const int idx = t + i * 256;
    const int rn = idx >> 4;        // col within tile
    const int ck = (idx & 15) * 4;  // k within tile (multiple of 4)
    ushort4 o;
    o.x = f2bf(tile[ck + 0][rn]);
    o.y = f2bf(tile[ck + 1][rn]);
    o.z = f2bf(tile[ck + 2][rn]);
    o.w = f2bf(tile[ck + 3][rn]);
    const int kg    = k0 + ck;          // global k of o.x
    const int chunk = kg >> 3;
    const int e0    = kg & 7;           // 0 or 4
    *reinterpret_cast<ushort4*>(
        &Wt[((size_t)chunk * N_TOT + n0 + rn) * 8 + e0]) = o;
  }
}

// ---------------------------------------------------------------------------
// Kernel 2 (FUSED): out[16384][512] = mean-gather(E, words) @ W + bias.
// 512 blocks x 256 threads (4 waves), BM=32 rows, full N=512.
// Phase 1: barrier-free E gather -> A_lds[32][96 slots][8] bf16 (swizzled
//          slot = kt*8 + (seg ^ (row&7)); conflict-free b128 r/w).
// Phase 2: GEMM; A fragments from LDS, B fragments DIRECT from L2-resident
//          fragment-major Wt (no B staging, no per-K barriers).
// ~50 KB LDS -> 2-3 blocks/CU; neighbor block's gather overlaps our GEMM,
// keeping the CU's HBM E-stream continuous.
// ---------------------------------------------------------------------------
__global__ __launch_bounds__(256, 2) void fused_kernel(
    const int* __restrict__ words, const float* __restrict__ E,
    const ushort* __restrict__ Wt, const float* __restrict__ bias,
    float* __restrict__ out) {
  __shared__ ushort A_l[BM * NSLOT * 8];  // 48 KB
  __shared__ int   eoff_l[BM][4];
  __shared__ float msk_l[BM][4];
  __shared__ float scl_l[BM];

  const int t    = threadIdx.x;
  const int lane = t & 63;
  const int w    = t >> 6;   // 0..3: wave's 128-col slab
  const int bm   = blockIdx.x;

  // ---- per-row gather metadata (rows bm*32 .. +32) ----
  if (t < BM) {
    const int4 w4 =
        *reinterpret_cast<const int4*>(words + (size_t)(bm * BM + t) * 4);
    const int ids[4] = {w4.x, w4.y, w4.z, w4.w};
    float cnt = 0.f;
#pragma unroll
    for (int f = 0; f < 4; ++f) {
      eoff_l[t][f] = ids[f] * K_TOT;
      const float m = (ids[f] != 0) ? 1.f : 0.f;
      msk_l[t][f] = m;
      cnt += m;
    }
    scl_l[t] = (cnt > 0.f) ? (1.f / cnt) : 0.f;
  }
  __syncthreads();

  // ---- phase 1: gather + mean, thread t covers (row sr, 8-elem seg ss) ----
  const int sr = t >> 3;         // 0..31
  const int ss = t & 7;          // 0..7
  const int sw = ss ^ (sr & 7);  // swizzled slot within each kt-group
  const float4* pf[4];
#pragma unroll
  for (int f = 0; f < 4; ++f)
    pf[f] = reinterpret_cast<const float4*>(E + eoff_l[sr][f] + ss * 8);
  const float m0 = msk_l[sr][0], m1 = msk_l[sr][1];
  const float m2 = msk_l[sr][2], m3 = msk_l[sr][3];
  const float scl = scl_l[sr];

#define A_LOAD(va, kt)                                                       \
  do {                                                                       \
    _Pragma("unroll") for (int f = 0; f < 4; ++f) {                          \
      va[2 * f + 0] = pf[f][(kt) * 16 + 0];                                  \
      va[2 * f + 1] = pf[f][(kt) * 16 + 1];                                  \
    }                                                                        \
  } while (0)

#define A_MATH(va, kt)                                                       \
  do {                                                                       \
    float s[8];                                                              \
    _Pragma("unroll") for (int j = 0; j < 4; ++j) {                          \
      s[j] = (va[0][j] * m0 + va[2][j] * m1 + va[4][j] * m2 + va[6][j] * m3) \
             * scl;                                                          \
      s[4 + j] =                                                             \
          (va[1][j] * m0 + va[3][j] * m1 + va[5][j] * m2 + va[7][j] * m3) *  \
          scl;                                                               \
    }                                                                        \
    uint4 o;                                                                 \
    o.x = pack2(s[0], s[1]); o.y = pack2(s[2], s[3]);                        \
    o.z = pack2(s[4], s[5]); o.w = pack2(s[6], s[7]);                        \
    *reinterpret_cast<uint4*>(&A_l[((sr) * NSLOT + (kt) * 8 + sw) * 8]) = o; \
  } while (0)

  {
    float4 vaA[8], vaB[8];
    A_LOAD(vaA, 0);
    A_LOAD(vaB, 1);
#pragma unroll
    for (int kt = 0; kt < NT; kt += 2) {
      A_MATH(vaA, kt);
      if (kt + 2 < NT) A_LOAD(vaA, kt + 2);
      A_MATH(vaB, kt + 1);
      if (kt + 3 < NT) A_LOAD(vaB, kt + 3);
    }
  }
#undef A_LOAD
#undef A_MATH
  __syncthreads();  // A tile complete; only barrier in the kernel

  // ---- phase 2: GEMM. acc = wave's 32 rows x 128 cols ----
  f32x4 acc[2][8];
#pragma unroll
  for (int m = 0; m < 2; ++m)
#pragma unroll
    for (int n = 0; n < 8; ++n) acc[m][n] = (f32x4){0.f, 0.f, 0.f, 0.f};

  const int colBase = w * 128 + (lane & 15);
  const int rsel    = lane & 15;   // row-within-16 for A, col-within-16 for B
  const int ksel    = lane >> 4;   // 0..3

#pragma unroll 2
  for (int kt = 0; kt < NT; ++kt) {
#pragma unroll
    for (int kk = 0; kk < 2; ++kk) {
      const int ks = kk * 4 + ksel;  // 0..7 (8-elem k-chunk within kt)
      bf16x8 af[2], bfr[8];
#pragma unroll
      for (int m = 0; m < 2; ++m) {
        const int row = m * 16 + rsel;
        af[m] = *reinterpret_cast<const bf16x8*>(
            &A_l[(row * NSLOT + kt * 8 + (ks ^ (row & 7))) * 8]);
      }
#pragma unroll
      for (int n = 0; n < 8; ++n) {
        bfr[n] = *reinterpret_cast<const bf16x8*>(
            &Wt[((size_t)(kt * 8 + ks) * N_TOT + colBase + n * 16) * 8]);
      }
#pragma unroll
      for (int m = 0; m < 2; ++m)
#pragma unroll
        for (int n = 0; n < 8; ++n)
          acc[m][n] = __builtin_amdgcn_mfma_f32_16x16x32_bf16(
              af[m], bfr[n], acc[m][n], 0, 0, 0);
    }
  }

  // ---- epilogue: C col = lane&15 (+16n), row = (lane>>4)*4 + j (+16m) ----
  const int row0 = bm * BM + (ksel << 2);
#pragma unroll
  for (int n = 0; n < 8; ++n) {
    const float bv = bias[colBase + n * 16];
#pragma unroll
    for (int m = 0; m < 2; ++m) {
#pragma unroll
      for (int j = 0; j < 4; ++j) {
        __builtin_nontemporal_store(
            acc[m][n][j] + bv,
            &out[(size_t)(row0 + m * 16 + j) * N_TOT + colBase + n * 16]);
      }
    }
  }
}

// ---------------------------------------------------------------------------
extern "C" void kernel_launch(void* const* d_in, const int* in_sizes, int n_in,
                              void* d_out, int out_size, void* d_ws,
                              size_t ws_size, hipStream_t stream) {
  const int*   words = (const int*)d_in[0];
  const float* E     = (const float*)d_in[1];
  const float* W     = (const float*)d_in[2];
  const float* b     = (const float*)d_in[3];
  float* out = (float*)d_out;

  ushort* Wtws = (ushort*)d_ws;  // 512*768 bf16, fragment-major

  hipLaunchKernelGGL(wt_kernel, dim3(K_TOT / 64, N_TOT / 64), dim3(256), 0,
                     stream, W, Wtws);
  hipLaunchKernelGGL(fused_kernel, dim3(M_TOT / BM), dim3(256), 0, stream,
                     words, E, Wtws, b, out);
}

// Round 8
// 54.213 us; speedup vs baseline: 1.1803x; 1.0045x over previous
//
#include <hip/hip_runtime.h>
#include <hip/hip_bf16.h>

// Problem dims (fixed by reference): B=64 S=256 F=4 V=50257 H=768 D=512
#define M_TOT 16384   // B*S
#define K_TOT 768     // H
#define N_TOT 512     // D
#define NT 12         // K_TOT / 64 K-chunks
#define NSLOT 96      // 16B-slots per A row (768*2B / 16B)

typedef __attribute__((ext_vector_type(8))) __bf16 bf16x8;
typedef __attribute__((ext_vector_type(4))) float f32x4;

static __device__ __forceinline__ ushort f2bf(float x) {
  union { float f; unsigned int u; } v; v.f = x;
  unsigned int r = v.u + 0x7fffu + ((v.u >> 16) & 1u);
  return (ushort)(r >> 16);
}
static __device__ __forceinline__ unsigned pack2(float lo, float hi) {
  return (unsigned)f2bf(lo) | ((unsigned)f2bf(hi) << 16);
}

// ---------------------------------------------------------------------------
// Kernel 1: W[768][512] f32 -> Wt_frag bf16 fragment-major:
//   W[k][col] -> Wt[ ((k>>3)*512 + col)*8 + (k&7) ]
// ---------------------------------------------------------------------------
__global__ __launch_bounds__(256) void wt_kernel(const float* __restrict__ W,
                                                 ushort* __restrict__ Wt) {
  __shared__ float tile[64][65];
  const int t  = threadIdx.x;
  const int k0 = blockIdx.x * 64;
  const int n0 = blockIdx.y * 64;
#pragma unroll
  for (int i = 0; i < 4; ++i) {
    const int idx = t + i * 256;
    const int r = idx >> 4;
    const int c = (idx & 15) * 4;
    const float4 v =
        *reinterpret_cast<const float4*>(W + (size_t)(k0 + r) * N_TOT + n0 + c);
    tile[r][c + 0] = v.x; tile[r][c + 1] = v.y;
    tile[r][c + 2] = v.z; tile[r][c + 3] = v.w;
  }
  __syncthreads();
#pragma unroll
  for (int i = 0; i < 4; ++i) {
    const int idx = t + i * 256;
    const int rn = idx >> 4;        // col within tile
    const int ck = (idx & 15) * 4;  // k within tile
    ushort4 o;
    o.x = f2bf(tile[ck + 0][rn]);
    o.y = f2bf(tile[ck + 1][rn]);
    o.z = f2bf(tile[ck + 2][rn]);
    o.w = f2bf(tile[ck + 3][rn]);
    const int kg    = k0 + ck;
    const int chunk = kg >> 3;
    const int e0    = kg & 7;
    *reinterpret_cast<ushort4*>(
        &Wt[((size_t)chunk * N_TOT + n0 + rn) * 8 + e0]) = o;
  }
}

// ---------------------------------------------------------------------------
// Kernel 2 (FUSED, pipelined): out = mean-gather(E, words) @ W + bias.
// 256 blocks (1/CU) x 512 threads (8 waves). Each block owns 64 rows as two
// 32-row sub-tiles T0/T1 with double-buffered A-LDS:
//   gather(T0); [GEMM(T0) || interleaved gather(T1)]; store(T0);
//   barrier; GEMM(T1); store(T1).
// The interleave makes HBM (E stream), L2 (B fragments) and MFMA concurrent.
// A-LDS slot-swizzled (slot = seg ^ (row&7)); B read direct from
// fragment-major Wt in L2 (no B staging, no per-K barriers).
// ---------------------------------------------------------------------------
__global__ __launch_bounds__(512, 1) void fused_kernel(
    const int* __restrict__ words, const float* __restrict__ E,
    const ushort* __restrict__ Wt, const float* __restrict__ bias,
    float* __restrict__ out) {
  __shared__ ushort A0[32 * NSLOT * 8];  // 48 KB
  __shared__ ushort A1[32 * NSLOT * 8];  // 48 KB
  __shared__ int   eoff_l[64][4];
  __shared__ float msk_l[64][4];
  __shared__ float scl_l[64];

  const int t    = threadIdx.x;
  const int lane = t & 63;
  const int w    = t >> 6;   // 0..7: wave's 64-col slab
  const int bm   = blockIdx.x;

  // ---- metadata for all 64 rows ----
  if (t < 64) {
    const int4 w4 =
        *reinterpret_cast<const int4*>(words + (size_t)(bm * 64 + t) * 4);
    const int ids[4] = {w4.x, w4.y, w4.z, w4.w};
    float cnt = 0.f;
#pragma unroll
    for (int f = 0; f < 4; ++f) {
      eoff_l[t][f] = ids[f] * K_TOT;
      const float m = (ids[f] != 0) ? 1.f : 0.f;
      msk_l[t][f] = m;
      cnt += m;
    }
    scl_l[t] = (cnt > 0.f) ? (1.f / cnt) : 0.f;
  }
  __syncthreads();

  // ---- gather thread mapping: 512 threads over 32 rows x 12 kt x 8 seg ----
  const int sr  = t >> 4;        // 0..31 row within sub-tile
  const int seg = t & 7;         // 16B segment
  const int ktb = (t >> 3) & 1;  // kt parity; group g covers kt = 2g+ktb
  const int sw  = seg ^ (sr & 7);

  // [S][f]: S=0 -> row sr, S=1 -> row 32+sr. Indexed only by literals.
  const float4* pf[2][4];
#pragma unroll
  for (int f = 0; f < 4; ++f) {
    pf[0][f] = reinterpret_cast<const float4*>(E + eoff_l[sr][f] + seg * 8);
    pf[1][f] =
        reinterpret_cast<const float4*>(E + eoff_l[32 + sr][f] + seg * 8);
  }
  const float mk[2][4] = {
      {msk_l[sr][0], msk_l[sr][1], msk_l[sr][2], msk_l[sr][3]},
      {msk_l[32 + sr][0], msk_l[32 + sr][1], msk_l[32 + sr][2],
       msk_l[32 + sr][3]}};
  const float sc[2] = {scl_l[sr], scl_l[32 + sr]};

  float4 vgA[8], vgB[8];  // two in-flight load groups (static names, rule #20)

#define G_LOAD(vg, S, g)                                                     \
  do {                                                                       \
    const int kt_ = 2 * (g) + ktb;                                           \
    _Pragma("unroll") for (int f = 0; f < 4; ++f) {                          \
      vg[2 * f + 0] = pf[S][f][kt_ * 16 + 0];                                \
      vg[2 * f + 1] = pf[S][f][kt_ * 16 + 1];                                \
    }                                                                        \
  } while (0)

#define G_MATH(vg, dst, S, g)                                                \
  do {                                                                       \
    const int kt_ = 2 * (g) + ktb;                                           \
    float s[8];                                                              \
    _Pragma("unroll") for (int j = 0; j < 4; ++j) {                          \
      s[j] = (vg[0][j] * mk[S][0] + vg[2][j] * mk[S][1] +                    \
              vg[4][j] * mk[S][2] + vg[6][j] * mk[S][3]) * sc[S];            \
      s[4 + j] = (vg[1][j] * mk[S][0] + vg[3][j] * mk[S][1] +                \
                  vg[5][j] * mk[S][2] + vg[7][j] * mk[S][3]) * sc[S];        \
    }                                                                        \
    uint4 o;                                                                 \
    o.x = pack2(s[0], s[1]); o.y = pack2(s[2], s[3]);                        \
    o.z = pack2(s[4], s[5]); o.w = pack2(s[6], s[7]);                        \
    *reinterpret_cast<uint4*>(&(dst)[(sr * NSLOT + kt_ * 8 + sw) * 8]) = o;  \
  } while (0)

  // ---- GEMM per-wave params ----
  const int rsel = lane & 15;
  const int ksel = lane >> 4;
  const int colBase = w * 64 + rsel;

  f32x4 acc[2][4];

#define COMPUTE(Asrc, kt)                                                    \
  do {                                                                       \
    _Pragma("unroll") for (int kk = 0; kk < 2; ++kk) {                       \
      const int ks = kk * 4 + ksel;                                          \
      bf16x8 af[2], bfr[4];                                                  \
      _Pragma("unroll") for (int m = 0; m < 2; ++m) {                        \
        const int r = m * 16 + rsel;                                         \
        af[m] = *reinterpret_cast<const bf16x8*>(                            \
            &(Asrc)[(r * NSLOT + (kt) * 8 + (ks ^ (r & 7))) * 8]);           \
      }                                                                      \
      _Pragma("unroll") for (int n = 0; n < 4; ++n)                          \
        bfr[n] = *reinterpret_cast<const bf16x8*>(                           \
            &Wt[((size_t)((kt) * 8 + ks) * N_TOT + colBase + n * 16) * 8]);  \
      _Pragma("unroll") for (int m = 0; m < 2; ++m)                          \
        _Pragma("unroll") for (int n = 0; n < 4; ++n)                        \
          acc[m][n] = __builtin_amdgcn_mfma_f32_16x16x32_bf16(               \
              af[m], bfr[n], acc[m][n], 0, 0, 0);                            \
    }                                                                        \
  } while (0)

#define EPILOGUE(T)                                                          \
  do {                                                                       \
    const int row0 = bm * 64 + (T) * 32 + (ksel << 2);                       \
    _Pragma("unroll") for (int n = 0; n < 4; ++n) {                          \
      const float bv = bias[colBase + n * 16];                               \
      _Pragma("unroll") for (int m = 0; m < 2; ++m) {                        \
        _Pragma("unroll") for (int j = 0; j < 4; ++j) {                      \
          __builtin_nontemporal_store(                                       \
              acc[m][n][j] + bv,                                             \
              &out[(size_t)(row0 + m * 16 + j) * N_TOT + colBase + n * 16]); \
        }                                                                    \
      }                                                                      \
    }                                                                        \
  } while (0)

  // ---- gather T0 (depth-2 pipeline, barrier-free) ----
  G_LOAD(vgA, 0, 0);
  G_LOAD(vgB, 0, 1);
  G_MATH(vgA, A0, 0, 0);  G_LOAD(vgA, 0, 2);
  G_MATH(vgB, A0, 0, 1);  G_LOAD(vgB, 0, 3);
  G_MATH(vgA, A0, 0, 2);  G_LOAD(vgA, 0, 4);
  G_MATH(vgB, A0, 0, 3);  G_LOAD(vgB, 0, 5);
  G_MATH(vgA, A0, 0, 4);
  G_MATH(vgB, A0, 0, 5);
  __syncthreads();  // A0 ready

  // ---- GEMM(T0) with interleaved gather(T1): issue early, math later ----
#pragma unroll
  for (int m = 0; m < 2; ++m)
#pragma unroll
    for (int n = 0; n < 4; ++n) acc[m][n] = (f32x4){0.f, 0.f, 0.f, 0.f};

  G_LOAD(vgA, 1, 0);
  COMPUTE(A0, 0);
  COMPUTE(A0, 1);
  G_LOAD(vgB, 1, 1);
  COMPUTE(A0, 2);
  G_MATH(vgA, A1, 1, 0);
  COMPUTE(A0, 3);
  G_LOAD(vgA, 1, 2);
  COMPUTE(A0, 4);
  G_MATH(vgB, A1, 1, 1);
  COMPUTE(A0, 5);
  G_LOAD(vgB, 1, 3);
  COMPUTE(A0, 6);
  G_MATH(vgA, A1, 1, 2);
  COMPUTE(A0, 7);
  G_LOAD(vgA, 1, 4);
  COMPUTE(A0, 8);
  G_MATH(vgB, A1, 1, 3);
  COMPUTE(A0, 9);
  G_LOAD(vgB, 1, 5);
  COMPUTE(A0, 10);
  G_MATH(vgA, A1, 1, 4);
  COMPUTE(A0, 11);
  G_MATH(vgB, A1, 1, 5);

  EPILOGUE(0);
  __syncthreads();  // A1 ready

  // ---- GEMM(T1) ----
#pragma unroll
  for (int m = 0; m < 2; ++m)
#pragma unroll
    for (int n = 0; n < 4; ++n) acc[m][n] = (f32x4){0.f, 0.f, 0.f, 0.f};
#pragma unroll
  for (int kt = 0; kt < NT; ++kt) COMPUTE(A1, kt);
  EPILOGUE(1);

#undef G_LOAD
#undef G_MATH
#undef COMPUTE
#undef EPILOGUE
}

// ---------------------------------------------------------------------------
extern "C" void kernel_launch(void* const* d_in, const int* in_sizes, int n_in,
                              void* d_out, int out_size, void* d_ws,
                              size_t ws_size, hipStream_t stream) {
  const int*   words = (const int*)d_in[0];
  const float* E     = (const float*)d_in[1];
  const float* W     = (const float*)d_in[2];
  const float* b     = (const float*)d_in[3];
  float* out = (float*)d_out;

  ushort* Wtws = (ushort*)d_ws;  // 512*768 bf16, fragment-major

  hipLaunchKernelGGL(wt_kernel, dim3(K_TOT / 64, N_TOT / 64), dim3(256), 0,
                     stream, W, Wtws);
  hipLaunchKernelGGL(fused_kernel, dim3(M_TOT / 64), dim3(512), 0, stream,
                     words, E, Wtws, b, out);
}